// Round 8
// baseline (561.952 us; speedup 1.0000x reference)
//
#include <hip/hip_runtime.h>
#include <hip/hip_bf16.h>

#define N_NODES 8192
#define IN_F 512
#define OUT_F 128
#define KSHIFT 3
#define KP (1 << KSHIFT)          // 8 k-partitions
#define COLS_PER (N_NODES / KP)   // 1024 cols per partition
#define NCHUNK (COLS_PER / 256)   // 4 chunks of 256 cols
#define LOG2E 1.4426950408889634f

typedef unsigned short u16;
typedef unsigned int u32;
typedef unsigned long long u64;
typedef short s16x8 __attribute__((ext_vector_type(8)));
typedef float f32x4 __attribute__((ext_vector_type(4)));
typedef u32 u32x4 __attribute__((ext_vector_type(4)));
typedef int i32x4 __attribute__((ext_vector_type(4)));

__device__ __forceinline__ u16 f2bf(float f) {
    union { float f; unsigned u; } x; x.f = f;
    unsigned r = x.u + 0x7FFFu + ((x.u >> 16) & 1u);
    return (u16)(r >> 16);
}

// HW pack: v_cvt_pk_bf16_f32 (rne) -> u32 (lo=a, hi=b)
__device__ __forceinline__ u32 packbf2(float a, float b) {
    __hip_bfloat162 h = __float22bfloat162_rn(make_float2(a, b));
    u32 u; __builtin_memcpy(&u, &h, 4);
    return u;
}

// edge weight: exp(sigmoid(alpha)) or 0 if masked
__device__ __forceinline__ float edge_p(float wh1, float w2, int keep) {
    float alpha = wh1 + w2;
    float e = exp2f(-LOG2E * alpha);
    float s = __builtin_amdgcn_rcpf(1.0f + e);
    float p = exp2f(LOG2E * s);
    return keep ? p : 0.0f;
}

// ---- K0: repack W [512x128] fp32 -> bf16 MFMA B-fragment layout
__global__ void repack_W(const float* __restrict__ W, u16* __restrict__ W_frag) {
    int tid = blockIdx.x * 256 + threadIdx.x;   // 0..65535
    int j = tid & 7;
    int lane = (tid >> 3) & 63;
    int nt = (tid >> 9) & 7;
    int kt = tid >> 12;
    int k = kt * 32 + (lane >> 4) * 8 + j;
    int n = nt * 16 + (lane & 15);
    W_frag[tid] = f2bf(W[k * OUT_F + n]);
}

// ---- Wa1 = W@a1, Wa2 = W@a2 (fp32, 512 each)
__global__ void compute_Wa(const float* __restrict__ W, const float* __restrict__ a1,
                           const float* __restrict__ a2,
                           float* __restrict__ Wa1, float* __restrict__ Wa2) {
    int k = blockIdx.x * 256 + threadIdx.x;
    if (k >= IN_F) return;
    float s1 = 0.f, s2 = 0.f;
    #pragma unroll 8
    for (int n = 0; n < OUT_F; n++) {
        float w = W[k * OUT_F + n];
        s1 += w * a1[n];
        s2 += w * a2[n];
    }
    Wa1[k] = s1; Wa2[k] = s2;
}

// ---- K1: h = X@W (bf16 MFMA), scatter h to B-frag layout; Wh = X@Wa (fp32).
// Round-5-proven shape: grid 512 blocks x 256 thr; block = 16 rows; wave w
// handles nt = 2w, 2w+1 (X rows L1-shared across the block's 4 waves).
__global__ __launch_bounds__(256)
void gemm_h(const float* __restrict__ X, const u16* __restrict__ W_frag,
            const float* __restrict__ Wa1, const float* __restrict__ Wa2,
            float* __restrict__ Wh1, float* __restrict__ Wh2,
            u16* __restrict__ h_frag) {
    int tid = threadIdx.x;
    int wave = tid >> 6;
    int lane = tid & 63;
    int quad = lane >> 4;
    int lid = lane & 15;
    int rbase = blockIdx.x * 16;
    const float* xrow = X + (size_t)(rbase + lid) * IN_F;
    const s16x8* Wf = (const s16x8*)W_frag;
    f32x4 acc0 = {}, acc1 = {};
    float p1 = 0.f, p2 = 0.f;
    int nt0 = wave * 2;

    for (int kt = 0; kt < 16; kt++) {
        int k0 = kt * 32 + quad * 8;
        float4 x0 = *(const float4*)(xrow + k0);
        float4 x1 = *(const float4*)(xrow + k0 + 4);
        u32x4 uv;
        uv.x = packbf2(x0.x, x0.y); uv.y = packbf2(x0.z, x0.w);
        uv.z = packbf2(x1.x, x1.y); uv.w = packbf2(x1.z, x1.w);
        s16x8 a = __builtin_bit_cast(s16x8, uv);
        if (wave == 0) {
            float4 wa = *(const float4*)(Wa1 + k0);
            float4 wb = *(const float4*)(Wa1 + k0 + 4);
            float4 wc = *(const float4*)(Wa2 + k0);
            float4 wd = *(const float4*)(Wa2 + k0 + 4);
            p1 += x0.x*wa.x + x0.y*wa.y + x0.z*wa.z + x0.w*wa.w
                + x1.x*wb.x + x1.y*wb.y + x1.z*wb.z + x1.w*wb.w;
            p2 += x0.x*wc.x + x0.y*wc.y + x0.z*wc.z + x0.w*wc.w
                + x1.x*wd.x + x1.y*wd.y + x1.z*wd.z + x1.w*wd.w;
        }
        s16x8 b0 = Wf[(kt * 8 + nt0) * 64 + lane];
        s16x8 b1 = Wf[(kt * 8 + nt0 + 1) * 64 + lane];
        acc0 = __builtin_amdgcn_mfma_f32_16x16x32_bf16(a, b0, acc0, 0, 0, 0);
        acc1 = __builtin_amdgcn_mfma_f32_16x16x32_bf16(a, b1, acc1, 0, 0, 0);
    }

    #pragma unroll
    for (int reg = 0; reg < 4; reg++) {
        int row = rbase + quad * 4 + reg;
        int ktile = row >> 5, kl = row & 31;
        int lane2 = (kl >> 3) * 16 + lid, j2 = kl & 7;
        h_frag[(size_t)((ktile * 8 + nt0) * 64 + lane2) * 8 + j2] = f2bf(acc0[reg]);
        h_frag[(size_t)((ktile * 8 + nt0 + 1) * 64 + lane2) * 8 + j2] = f2bf(acc1[reg]);
    }
    if (wave == 0) {
        p1 += __shfl_xor(p1, 16, 64); p1 += __shfl_xor(p1, 32, 64);
        p2 += __shfl_xor(p2, 16, 64); p2 += __shfl_xor(p2, 32, 64);
        if (lane < 16) { Wh1[rbase + lid] = p1; Wh2[rbase + lid] = p2; }
    }
}

// ---- K2: fused mask+sigmoid+exp+P@h with COALESCED adj staging.
// Block = 128 rows; wave w owns rows [w*32, w*32+32). Per 256-col chunk the
// wave streams its 32 rows with 1 KB contiguous bursts (lane i -> cols
// 4i..4i+3), ballot-compresses each row to 4x u64, parks them in wave-private
// LDS (double-buffered, no barriers), then runs 8 MFMA k-steps off the bits.
// grid = 64 rtiles x KP kparts.
__global__ __launch_bounds__(256)
void attn_kernel(const int* __restrict__ adj, const float* __restrict__ Wh1,
                 const float* __restrict__ Wh2, const u16* __restrict__ h_frag,
                 float* __restrict__ out_part, float* __restrict__ sum_part) {
    __shared__ u64 lds_bits[4][2][32][4];   // [wave][buf][row][ballot] = 8 KB

    int tid = threadIdx.x;
    int wave = tid >> 6;
    int lane = tid & 63;
    int quad = lane >> 4;
    int lid = lane & 15;
    int rtile = blockIdx.x >> KSHIFT;
    int kh = blockIdx.x & (KP - 1);
    int rbase = rtile * 128 + wave * 32;
    int r0 = rbase + lid, r1 = r0 + 16;

    float wh10 = Wh1[r0], wh11 = Wh1[r1];
    f32x4 acc0[8] = {}, acc1[8] = {};
    float ps0 = 0.f, ps1 = 0.f;
    const s16x8* Hf = (const s16x8*)h_frag;

    for (int chunk = 0; chunk < NCHUNK; chunk++) {
        int buf = chunk & 1;
        int colbase = kh * COLS_PER + chunk * 256;

        // ---- stage: 32 rows x 256 cols -> bits (1 KB coalesced burst per row)
        #pragma unroll 4
        for (int r = 0; r < 32; r++) {
            const i32x4* p = (const i32x4*)(adj + (size_t)(rbase + r) * N_NODES + colbase);
            i32x4 v = p[lane];
            u64 b0 = __ballot(v.x > 0);   // bit L -> col 4L+0
            u64 b1 = __ballot(v.y > 0);
            u64 b2 = __ballot(v.z > 0);
            u64 b3 = __ballot(v.w > 0);
            if (lane == 0) {
                lds_bits[wave][buf][r][0] = b0;
                lds_bits[wave][buf][r][1] = b1;
                lds_bits[wave][buf][r][2] = b2;
                lds_bits[wave][buf][r][3] = b3;
            }
        }

        // pull this lane's two rows' bits into registers
        u64 Ba[4], Bb[4];
        #pragma unroll
        for (int j = 0; j < 4; j++) {
            Ba[j] = lds_bits[wave][buf][lid][j];
            Bb[j] = lds_bits[wave][buf][lid + 16][j];
        }

        // ---- compute: 8 k-steps of 32 cols
        #pragma unroll
        for (int ktl = 0; ktl < 8; ktl++) {
            int sh = ktl * 8 + quad * 2;           // bit offset within u64
            int col0 = colbase + ktl * 32 + quad * 8;
            int ktg = (colbase >> 5) + ktl;        // global k-tile for Hf
            float4 w20 = *(const float4*)(Wh2 + col0);
            float4 w21 = *(const float4*)(Wh2 + col0 + 4);
            float w2v[8] = {w20.x, w20.y, w20.z, w20.w, w21.x, w21.y, w21.z, w21.w};

            float ev[8], fv[8];
            #pragma unroll
            for (int j2 = 0; j2 < 8; j2++) {
                int ka = (int)((Ba[j2 & 3] >> (sh + (j2 >> 2))) & 1ull);
                int kb = (int)((Bb[j2 & 3] >> (sh + (j2 >> 2))) & 1ull);
                ev[j2] = edge_p(wh10, w2v[j2], ka);
                fv[j2] = edge_p(wh11, w2v[j2], kb);
            }
            ps0 += ((ev[0] + ev[1]) + (ev[2] + ev[3])) + ((ev[4] + ev[5]) + (ev[6] + ev[7]));
            ps1 += ((fv[0] + fv[1]) + (fv[2] + fv[3])) + ((fv[4] + fv[5]) + (fv[6] + fv[7]));
            u32x4 uv0, uv1;
            uv0.x = packbf2(ev[0], ev[1]); uv0.y = packbf2(ev[2], ev[3]);
            uv0.z = packbf2(ev[4], ev[5]); uv0.w = packbf2(ev[6], ev[7]);
            uv1.x = packbf2(fv[0], fv[1]); uv1.y = packbf2(fv[2], fv[3]);
            uv1.z = packbf2(fv[4], fv[5]); uv1.w = packbf2(fv[6], fv[7]);
            s16x8 af0 = __builtin_bit_cast(s16x8, uv0);
            s16x8 af1 = __builtin_bit_cast(s16x8, uv1);

            #pragma unroll
            for (int nt = 0; nt < 8; nt++) {
                s16x8 b = Hf[(ktg * 8 + nt) * 64 + lane];
                acc0[nt] = __builtin_amdgcn_mfma_f32_16x16x32_bf16(af0, b, acc0[nt], 0, 0, 0);
                acc1[nt] = __builtin_amdgcn_mfma_f32_16x16x32_bf16(af1, b, acc1[nt], 0, 0, 0);
            }
        }
    }

    ps0 += __shfl_xor(ps0, 16, 64); ps0 += __shfl_xor(ps0, 32, 64);
    ps1 += __shfl_xor(ps1, 16, 64); ps1 += __shfl_xor(ps1, 32, 64);
    if (quad == 0) {
        sum_part[(size_t)kh * N_NODES + r0] = ps0;
        sum_part[(size_t)kh * N_NODES + r1] = ps1;
    }

    #pragma unroll
    for (int nt = 0; nt < 8; nt++) {
        #pragma unroll
        for (int reg = 0; reg < 4; reg++) {
            int row0 = rbase + quad * 4 + reg;
            int col = nt * 16 + lid;
            out_part[((size_t)kh * N_NODES + row0) * OUT_F + col] = acc0[nt][reg];
            out_part[((size_t)kh * N_NODES + row0 + 16) * OUT_F + col] = acc1[nt][reg];
        }
    }
}

// ---- K3: out = (sum_k part_k) / (sum_k rowsum_k)
__global__ void finalize(const float* __restrict__ out_part,
                         const float* __restrict__ sum_part,
                         float* __restrict__ out) {
    int gid = blockIdx.x * 256 + threadIdx.x;
    int i = gid >> 7;
    float s = 0.f, v = 0.f;
    #pragma unroll
    for (int kh = 0; kh < KP; kh++) {
        s += sum_part[(size_t)kh * N_NODES + i];
        v += out_part[(size_t)kh * N_NODES * OUT_F + gid];
    }
    out[gid] = v / s;
}

extern "C" void kernel_launch(void* const* d_in, const int* in_sizes, int n_in,
                              void* d_out, int out_size, void* d_ws, size_t ws_size,
                              hipStream_t stream) {
    const float* X   = (const float*)d_in[0];
    const int*   adj = (const int*)d_in[1];
    const float* W   = (const float*)d_in[2];
    const float* a1  = (const float*)d_in[3];
    const float* a2  = (const float*)d_in[4];

    const size_t BASE = (size_t)4 << 20;   // fixed region: Wh/Wa/W_frag/h_frag
    char* ws = (char*)d_ws;
    float* Wh1 = (float*)(ws);                         // 32 KB
    float* Wh2 = (float*)(ws + (32 << 10));            // 32 KB
    float* Wa1 = (float*)(ws + (64 << 10));            // 2 KB
    float* Wa2 = (float*)(ws + (66 << 10));            // 2 KB
    u16* W_frag = (u16*)(ws + (128 << 10));            // 128 KB
    u16* h_frag = (u16*)(ws + (256 << 10));            // 2 MB (ends at 2.25 MB < 4 MB)
    float* out_part = (float*)(ws + BASE);             // KP * 4 MB = 32 MB
    float* sum_part = (float*)(ws + BASE + ((size_t)KP << 22));  // KP * 32 KB
    float* out = (float*)d_out;

    hipLaunchKernelGGL(repack_W, dim3(256), dim3(256), 0, stream, W, W_frag);
    hipLaunchKernelGGL(compute_Wa, dim3(2), dim3(256), 0, stream, W, a1, a2, Wa1, Wa2);
    hipLaunchKernelGGL(gemm_h, dim3(512), dim3(256), 0, stream,
                       X, W_frag, Wa1, Wa2, Wh1, Wh2, h_frag);
    hipLaunchKernelGGL(attn_kernel, dim3(64 * KP), dim3(256), 0, stream,
                       adj, Wh1, Wh2, h_frag, out_part, sum_part);
    hipLaunchKernelGGL(finalize, dim3((N_NODES * OUT_F) / 256), dim3(256), 0, stream,
                       out_part, sum_part, out);
}

// Round 9
// 438.029 us; speedup vs baseline: 1.2829x; 1.2829x over previous
//
#include <hip/hip_runtime.h>
#include <hip/hip_bf16.h>

#define N_NODES 8192
#define IN_F 512
#define OUT_F 128
#define KSHIFT 3
#define KP (1 << KSHIFT)          // 8 k-partitions
#define KT_PER (256 >> KSHIFT)    // 32 k-tiles of 32 cols each
#define LOG2E 1.4426950408889634f

typedef unsigned short u16;
typedef unsigned int u32;
typedef short s16x8 __attribute__((ext_vector_type(8)));
typedef float f32x4 __attribute__((ext_vector_type(4)));
typedef u32 u32x4 __attribute__((ext_vector_type(4)));

__device__ __forceinline__ u16 f2bf(float f) {
    union { float f; unsigned u; } x; x.f = f;
    unsigned r = x.u + 0x7FFFu + ((x.u >> 16) & 1u);
    return (u16)(r >> 16);
}

// HW pack: v_cvt_pk_bf16_f32 (rne) -> u32 (lo=a, hi=b)
__device__ __forceinline__ u32 packbf2(float a, float b) {
    __hip_bfloat162 h = __float22bfloat162_rn(make_float2(a, b));
    u32 u; __builtin_memcpy(&u, &h, 4);
    return u;
}

// edge weight: exp(sigmoid(alpha)) or 0 if masked
__device__ __forceinline__ float edge_p(float wh1, float w2, int keep) {
    float alpha = wh1 + w2;
    float e = exp2f(-LOG2E * alpha);
    float s = __builtin_amdgcn_rcpf(1.0f + e);
    float p = exp2f(LOG2E * s);
    return keep ? p : 0.0f;
}

// ---- K0: repack W [512x128] fp32 -> bf16 MFMA B-fragment layout
__global__ void repack_W(const float* __restrict__ W, u16* __restrict__ W_frag) {
    int tid = blockIdx.x * 256 + threadIdx.x;   // 0..65535
    int j = tid & 7;
    int lane = (tid >> 3) & 63;
    int nt = (tid >> 9) & 7;
    int kt = tid >> 12;
    int k = kt * 32 + (lane >> 4) * 8 + j;
    int n = nt * 16 + (lane & 15);
    W_frag[tid] = f2bf(W[k * OUT_F + n]);
}

// ---- Wa1 = W@a1, Wa2 = W@a2 (fp32, 512 each)
__global__ void compute_Wa(const float* __restrict__ W, const float* __restrict__ a1,
                           const float* __restrict__ a2,
                           float* __restrict__ Wa1, float* __restrict__ Wa2) {
    int k = blockIdx.x * 256 + threadIdx.x;
    if (k >= IN_F) return;
    float s1 = 0.f, s2 = 0.f;
    #pragma unroll 8
    for (int n = 0; n < OUT_F; n++) {
        float w = W[k * OUT_F + n];
        s1 += w * a1[n];
        s2 += w * a2[n];
    }
    Wa1[k] = s1; Wa2[k] = s2;
}

// ---- K1: h = X@W (bf16 MFMA), scatter h to B-frag layout; Wh = X@Wa (fp32).
// R5-proven shape: grid 512 blocks x 256 thr; block = 16 rows; wave w
// handles nt = 2w, 2w+1 (X rows L1-shared across the block's 4 waves).
__global__ __launch_bounds__(256)
void gemm_h(const float* __restrict__ X, const u16* __restrict__ W_frag,
            const float* __restrict__ Wa1, const float* __restrict__ Wa2,
            float* __restrict__ Wh1, float* __restrict__ Wh2,
            u16* __restrict__ h_frag) {
    int tid = threadIdx.x;
    int wave = tid >> 6;
    int lane = tid & 63;
    int quad = lane >> 4;
    int lid = lane & 15;
    int rbase = blockIdx.x * 16;
    const float* xrow = X + (size_t)(rbase + lid) * IN_F;
    const s16x8* Wf = (const s16x8*)W_frag;
    f32x4 acc0 = {}, acc1 = {};
    float p1 = 0.f, p2 = 0.f;
    int nt0 = wave * 2;

    for (int kt = 0; kt < 16; kt++) {
        int k0 = kt * 32 + quad * 8;
        float4 x0 = *(const float4*)(xrow + k0);
        float4 x1 = *(const float4*)(xrow + k0 + 4);
        u32x4 uv;
        uv.x = packbf2(x0.x, x0.y); uv.y = packbf2(x0.z, x0.w);
        uv.z = packbf2(x1.x, x1.y); uv.w = packbf2(x1.z, x1.w);
        s16x8 a = __builtin_bit_cast(s16x8, uv);
        if (wave == 0) {
            float4 wa = *(const float4*)(Wa1 + k0);
            float4 wb = *(const float4*)(Wa1 + k0 + 4);
            float4 wc = *(const float4*)(Wa2 + k0);
            float4 wd = *(const float4*)(Wa2 + k0 + 4);
        p1 += x0.x*wa.x + x0.y*wa.y + x0.z*wa.z + x0.w*wa.w
            + x1.x*wb.x + x1.y*wb.y + x1.z*wb.z + x1.w*wb.w;
        p2 += x0.x*wc.x + x0.y*wc.y + x0.z*wc.z + x0.w*wc.w
            + x1.x*wd.x + x1.y*wd.y + x1.z*wd.z + x1.w*wd.w;
        }
        s16x8 b0 = Wf[(kt * 8 + nt0) * 64 + lane];
        s16x8 b1 = Wf[(kt * 8 + nt0 + 1) * 64 + lane];
        acc0 = __builtin_amdgcn_mfma_f32_16x16x32_bf16(a, b0, acc0, 0, 0, 0);
        acc1 = __builtin_amdgcn_mfma_f32_16x16x32_bf16(a, b1, acc1, 0, 0, 0);
    }

    #pragma unroll
    for (int reg = 0; reg < 4; reg++) {
        int row = rbase + quad * 4 + reg;
        int ktile = row >> 5, kl = row & 31;
        int lane2 = (kl >> 3) * 16 + lid, j2 = kl & 7;
        h_frag[(size_t)((ktile * 8 + nt0) * 64 + lane2) * 8 + j2] = f2bf(acc0[reg]);
        h_frag[(size_t)((ktile * 8 + nt0 + 1) * 64 + lane2) * 8 + j2] = f2bf(acc1[reg]);
    }
    if (wave == 0) {
        p1 += __shfl_xor(p1, 16, 64); p1 += __shfl_xor(p1, 32, 64);
        p2 += __shfl_xor(p2, 16, 64); p2 += __shfl_xor(p2, 32, 64);
        if (lane < 16) { Wh1[rbase + lid] = p1; Wh2[rbase + lid] = p2; }
    }
}

// ---- K2: fused mask+sigmoid+exp+P@h. adj read directly (exactly once across
// the grid). 32 rows/wave, block = 128 rows; grid = 64 rtiles x KP kparts.
// CRITICAL: kt loop kept ROLLED (#pragma unroll 1) — compact body avoids the
// I-cache thrash that pinned R2/R8's unrolled variants at ~260 us.
__global__ __launch_bounds__(256)
void attn_kernel(const int* __restrict__ adj, const float* __restrict__ Wh1,
                 const float* __restrict__ Wh2, const u16* __restrict__ h_frag,
                 float* __restrict__ out_part, float* __restrict__ sum_part) {
    int tid = threadIdx.x;
    int wave = tid >> 6;
    int lane = tid & 63;
    int quad = lane >> 4;
    int lid = lane & 15;
    int rtile = blockIdx.x >> KSHIFT;
    int kh = blockIdx.x & (KP - 1);
    int rbase = rtile * 128 + wave * 32;
    int r0 = rbase + lid, r1 = r0 + 16;

    float wh10 = Wh1[r0], wh11 = Wh1[r1];
    f32x4 acc0[8] = {}, acc1[8] = {};
    float ps0 = 0.f, ps1 = 0.f;
    const s16x8* Hf = (const s16x8*)h_frag;
    const int* adjrow0 = adj + (size_t)r0 * N_NODES;
    const int* adjrow1 = adj + (size_t)r1 * N_NODES;

    const int kt0 = kh * KT_PER;
    #pragma unroll 1
    for (int kt = kt0; kt < kt0 + KT_PER; kt++) {
        int k0 = kt * 32 + quad * 8;
        int4 aj0a = *(const int4*)(adjrow0 + k0);
        int4 aj0b = *(const int4*)(adjrow0 + k0 + 4);
        int4 aj1a = *(const int4*)(adjrow1 + k0);
        int4 aj1b = *(const int4*)(adjrow1 + k0 + 4);
        float4 w20 = *(const float4*)(Wh2 + k0);
        float4 w21 = *(const float4*)(Wh2 + k0 + 4);

        float e0 = edge_p(wh10, w20.x, aj0a.x), e1 = edge_p(wh10, w20.y, aj0a.y);
        float e2 = edge_p(wh10, w20.z, aj0a.z), e3 = edge_p(wh10, w20.w, aj0a.w);
        float e4 = edge_p(wh10, w21.x, aj0b.x), e5 = edge_p(wh10, w21.y, aj0b.y);
        float e6 = edge_p(wh10, w21.z, aj0b.z), e7 = edge_p(wh10, w21.w, aj0b.w);
        ps0 += ((e0 + e1) + (e2 + e3)) + ((e4 + e5) + (e6 + e7));
        u32x4 uv0;
        uv0.x = packbf2(e0, e1); uv0.y = packbf2(e2, e3);
        uv0.z = packbf2(e4, e5); uv0.w = packbf2(e6, e7);

        float f0 = edge_p(wh11, w20.x, aj1a.x), f1 = edge_p(wh11, w20.y, aj1a.y);
        float f2 = edge_p(wh11, w20.z, aj1a.z), f3 = edge_p(wh11, w20.w, aj1a.w);
        float f4 = edge_p(wh11, w21.x, aj1b.x), f5 = edge_p(wh11, w21.y, aj1b.y);
        float f6 = edge_p(wh11, w21.z, aj1b.z), f7 = edge_p(wh11, w21.w, aj1b.w);
        ps1 += ((f0 + f1) + (f2 + f3)) + ((f4 + f5) + (f6 + f7));
        u32x4 uv1;
        uv1.x = packbf2(f0, f1); uv1.y = packbf2(f2, f3);
        uv1.z = packbf2(f4, f5); uv1.w = packbf2(f6, f7);

        s16x8 af0 = __builtin_bit_cast(s16x8, uv0);
        s16x8 af1 = __builtin_bit_cast(s16x8, uv1);

        #pragma unroll
        for (int nt = 0; nt < 8; nt++) {
            s16x8 b = Hf[(kt * 8 + nt) * 64 + lane];
            acc0[nt] = __builtin_amdgcn_mfma_f32_16x16x32_bf16(af0, b, acc0[nt], 0, 0, 0);
            acc1[nt] = __builtin_amdgcn_mfma_f32_16x16x32_bf16(af1, b, acc1[nt], 0, 0, 0);
        }
    }

    ps0 += __shfl_xor(ps0, 16, 64); ps0 += __shfl_xor(ps0, 32, 64);
    ps1 += __shfl_xor(ps1, 16, 64); ps1 += __shfl_xor(ps1, 32, 64);
    if (quad == 0) {
        sum_part[(size_t)kh * N_NODES + r0] = ps0;
        sum_part[(size_t)kh * N_NODES + r1] = ps1;
    }

    #pragma unroll
    for (int nt = 0; nt < 8; nt++) {
        #pragma unroll
        for (int reg = 0; reg < 4; reg++) {
            int row0 = rbase + quad * 4 + reg;
            int col = nt * 16 + lid;
            out_part[((size_t)kh * N_NODES + row0) * OUT_F + col] = acc0[nt][reg];
            out_part[((size_t)kh * N_NODES + row0 + 16) * OUT_F + col] = acc1[nt][reg];
        }
    }
}

// ---- K3: out = (sum_k part_k) / (sum_k rowsum_k)
__global__ void finalize(const float* __restrict__ out_part,
                         const float* __restrict__ sum_part,
                         float* __restrict__ out) {
    int gid = blockIdx.x * 256 + threadIdx.x;
    int i = gid >> 7;
    float s = 0.f, v = 0.f;
    for (int kh = 0; kh < KP; kh++) {
        s += sum_part[(size_t)kh * N_NODES + i];
        v += out_part[(size_t)kh * N_NODES * OUT_F + gid];
    }
    out[gid] = v / s;
}

extern "C" void kernel_launch(void* const* d_in, const int* in_sizes, int n_in,
                              void* d_out, int out_size, void* d_ws, size_t ws_size,
                              hipStream_t stream) {
    const float* X   = (const float*)d_in[0];
    const int*   adj = (const int*)d_in[1];
    const float* W   = (const float*)d_in[2];
    const float* a1  = (const float*)d_in[3];
    const float* a2  = (const float*)d_in[4];

    const size_t BASE = (size_t)4 << 20;   // fixed region: Wh/Wa/W_frag/h_frag
    char* ws = (char*)d_ws;
    float* Wh1 = (float*)(ws);                         // 32 KB
    float* Wh2 = (float*)(ws + (32 << 10));            // 32 KB
    float* Wa1 = (float*)(ws + (64 << 10));            // 2 KB
    float* Wa2 = (float*)(ws + (66 << 10));            // 2 KB
    u16* W_frag = (u16*)(ws + (128 << 10));            // 128 KB
    u16* h_frag = (u16*)(ws + (256 << 10));            // 2 MB (ends at 2.25 MB < 4 MB)
    float* out_part = (float*)(ws + BASE);             // KP * 4 MB = 32 MB
    float* sum_part = (float*)(ws + BASE + ((size_t)KP << 22));  // KP * 32 KB
    float* out = (float*)d_out;

    hipLaunchKernelGGL(repack_W, dim3(256), dim3(256), 0, stream, W, W_frag);
    hipLaunchKernelGGL(compute_Wa, dim3(2), dim3(256), 0, stream, W, a1, a2, Wa1, Wa2);
    hipLaunchKernelGGL(gemm_h, dim3(512), dim3(256), 0, stream,
                       X, W_frag, Wa1, Wa2, Wh1, Wh2, h_frag);
    hipLaunchKernelGGL(attn_kernel, dim3(64 * KP), dim3(256), 0, stream,
                       adj, Wh1, Wh2, h_frag, out_part, sum_part);
    hipLaunchKernelGGL(finalize, dim3((N_NODES * OUT_F) / 256), dim3(256), 0, stream,
                       out_part, sum_part, out);
}

// Round 10
// 422.694 us; speedup vs baseline: 1.3295x; 1.0363x over previous
//
#include <hip/hip_runtime.h>
#include <hip/hip_bf16.h>

#define N_NODES 8192
#define IN_F 512
#define OUT_F 128
#define KSHIFT 4
#define KP (1 << KSHIFT)          // 16 k-partitions
#define KT_PER (256 >> KSHIFT)    // 16 k-tiles of 32 cols each
#define LOG2E 1.4426950408889634f

typedef unsigned short u16;
typedef unsigned int u32;
typedef short s16x8 __attribute__((ext_vector_type(8)));
typedef float f32x4 __attribute__((ext_vector_type(4)));
typedef u32 u32x4 __attribute__((ext_vector_type(4)));

__device__ __forceinline__ u16 f2bf(float f) {
    union { float f; unsigned u; } x; x.f = f;
    unsigned r = x.u + 0x7FFFu + ((x.u >> 16) & 1u);
    return (u16)(r >> 16);
}

// HW pack: v_cvt_pk_bf16_f32 (rne) -> u32 (lo=a, hi=b)
__device__ __forceinline__ u32 packbf2(float a, float b) {
    __hip_bfloat162 h = __float22bfloat162_rn(make_float2(a, b));
    u32 u; __builtin_memcpy(&u, &h, 4);
    return u;
}

// edge weight: exp(sigmoid(alpha)) or 0 if masked
__device__ __forceinline__ float edge_p(float wh1, float w2, int keep) {
    float alpha = wh1 + w2;
    float e = exp2f(-LOG2E * alpha);
    float s = __builtin_amdgcn_rcpf(1.0f + e);
    float p = exp2f(LOG2E * s);
    return keep ? p : 0.0f;
}

// ---- K0: repack W [512x128] fp32 -> bf16 MFMA B-fragment layout
__global__ void repack_W(const float* __restrict__ W, u16* __restrict__ W_frag) {
    int tid = blockIdx.x * 256 + threadIdx.x;   // 0..65535
    int j = tid & 7;
    int lane = (tid >> 3) & 63;
    int nt = (tid >> 9) & 7;
    int kt = tid >> 12;
    int k = kt * 32 + (lane >> 4) * 8 + j;
    int n = nt * 16 + (lane & 15);
    W_frag[tid] = f2bf(W[k * OUT_F + n]);
}

// ---- Wa1 = W@a1, Wa2 = W@a2 (fp32, 512 each)
__global__ void compute_Wa(const float* __restrict__ W, const float* __restrict__ a1,
                           const float* __restrict__ a2,
                           float* __restrict__ Wa1, float* __restrict__ Wa2) {
    int k = blockIdx.x * 256 + threadIdx.x;
    if (k >= IN_F) return;
    float s1 = 0.f, s2 = 0.f;
    #pragma unroll 8
    for (int n = 0; n < OUT_F; n++) {
        float w = W[k * OUT_F + n];
        s1 += w * a1[n];
        s2 += w * a2[n];
    }
    Wa1[k] = s1; Wa2[k] = s2;
}

// ---- K1: h = X@W (bf16 MFMA), scatter h to B-frag layout; Wh = X@Wa (fp32).
// R5-proven shape: grid 512 blocks x 256 thr; block = 16 rows; wave w
// handles nt = 2w, 2w+1 (X rows L1-shared across the block's 4 waves).
__global__ __launch_bounds__(256)
void gemm_h(const float* __restrict__ X, const u16* __restrict__ W_frag,
            const float* __restrict__ Wa1, const float* __restrict__ Wa2,
            float* __restrict__ Wh1, float* __restrict__ Wh2,
            u16* __restrict__ h_frag) {
    int tid = threadIdx.x;
    int wave = tid >> 6;
    int lane = tid & 63;
    int quad = lane >> 4;
    int lid = lane & 15;
    int rbase = blockIdx.x * 16;
    const float* xrow = X + (size_t)(rbase + lid) * IN_F;
    const s16x8* Wf = (const s16x8*)W_frag;
    f32x4 acc0 = {}, acc1 = {};
    float p1 = 0.f, p2 = 0.f;
    int nt0 = wave * 2;

    for (int kt = 0; kt < 16; kt++) {
        int k0 = kt * 32 + quad * 8;
        float4 x0 = *(const float4*)(xrow + k0);
        float4 x1 = *(const float4*)(xrow + k0 + 4);
        u32x4 uv;
        uv.x = packbf2(x0.x, x0.y); uv.y = packbf2(x0.z, x0.w);
        uv.z = packbf2(x1.x, x1.y); uv.w = packbf2(x1.z, x1.w);
        s16x8 a = __builtin_bit_cast(s16x8, uv);
        if (wave == 0) {
            float4 wa = *(const float4*)(Wa1 + k0);
            float4 wb = *(const float4*)(Wa1 + k0 + 4);
            float4 wc = *(const float4*)(Wa2 + k0);
            float4 wd = *(const float4*)(Wa2 + k0 + 4);
            p1 += x0.x*wa.x + x0.y*wa.y + x0.z*wa.z + x0.w*wa.w
                + x1.x*wb.x + x1.y*wb.y + x1.z*wb.z + x1.w*wb.w;
            p2 += x0.x*wc.x + x0.y*wc.y + x0.z*wc.z + x0.w*wc.w
                + x1.x*wd.x + x1.y*wd.y + x1.z*wd.z + x1.w*wd.w;
        }
        s16x8 b0 = Wf[(kt * 8 + nt0) * 64 + lane];
        s16x8 b1 = Wf[(kt * 8 + nt0 + 1) * 64 + lane];
        acc0 = __builtin_amdgcn_mfma_f32_16x16x32_bf16(a, b0, acc0, 0, 0, 0);
        acc1 = __builtin_amdgcn_mfma_f32_16x16x32_bf16(a, b1, acc1, 0, 0, 0);
    }

    #pragma unroll
    for (int reg = 0; reg < 4; reg++) {
        int row = rbase + quad * 4 + reg;
        int ktile = row >> 5, kl = row & 31;
        int lane2 = (kl >> 3) * 16 + lid, j2 = kl & 7;
        h_frag[(size_t)((ktile * 8 + nt0) * 64 + lane2) * 8 + j2] = f2bf(acc0[reg]);
        h_frag[(size_t)((ktile * 8 + nt0 + 1) * 64 + lane2) * 8 + j2] = f2bf(acc1[reg]);
    }
    if (wave == 0) {
        p1 += __shfl_xor(p1, 16, 64); p1 += __shfl_xor(p1, 32, 64);
        p2 += __shfl_xor(p2, 16, 64); p2 += __shfl_xor(p2, 32, 64);
        if (lane < 16) { Wh1[rbase + lid] = p1; Wh2[rbase + lid] = p2; }
    }
}

// ---- K2: fused mask+sigmoid+exp+P@h. adj read directly (exactly once across
// the grid). 32 rows/wave, block = 128 rows; grid = 64 rtiles x KP kparts.
// Rolled kt loop (compact body — R9-proven) + one-iteration REGISTER PREFETCH
// of the next adj tiles to overlap HBM latency with compute.
__global__ __launch_bounds__(256)
void attn_kernel(const int* __restrict__ adj, const float* __restrict__ Wh1,
                 const float* __restrict__ Wh2, const u16* __restrict__ h_frag,
                 float* __restrict__ out_part, float* __restrict__ sum_part) {
    int tid = threadIdx.x;
    int wave = tid >> 6;
    int lane = tid & 63;
    int quad = lane >> 4;
    int lid = lane & 15;
    int rtile = blockIdx.x >> KSHIFT;
    int kh = blockIdx.x & (KP - 1);
    int rbase = rtile * 128 + wave * 32;
    int r0 = rbase + lid, r1 = r0 + 16;

    float wh10 = Wh1[r0], wh11 = Wh1[r1];
    f32x4 acc0[8] = {}, acc1[8] = {};
    float ps0 = 0.f, ps1 = 0.f;
    const s16x8* Hf = (const s16x8*)h_frag;
    const int* adjrow0 = adj + (size_t)r0 * N_NODES;
    const int* adjrow1 = adj + (size_t)r1 * N_NODES;

    const int kt0 = kh * KT_PER;
    const int ktend = kt0 + KT_PER;

    // prefetch prologue: first iteration's adj tiles
    int kpf = kt0 * 32 + quad * 8;
    int4 A0a = *(const int4*)(adjrow0 + kpf);
    int4 A0b = *(const int4*)(adjrow0 + kpf + 4);
    int4 A1a = *(const int4*)(adjrow1 + kpf);
    int4 A1b = *(const int4*)(adjrow1 + kpf + 4);

    #pragma unroll 1
    for (int kt = kt0; kt < ktend; kt++) {
        int k0 = kt * 32 + quad * 8;
        // consume current, issue next-iteration loads immediately
        int4 aj0a = A0a, aj0b = A0b, aj1a = A1a, aj1b = A1b;
        int ktn = (kt + 1 < ktend) ? (kt + 1) : kt;   // clamp (no OOB)
        int k0n = ktn * 32 + quad * 8;
        A0a = *(const int4*)(adjrow0 + k0n);
        A0b = *(const int4*)(adjrow0 + k0n + 4);
        A1a = *(const int4*)(adjrow1 + k0n);
        A1b = *(const int4*)(adjrow1 + k0n + 4);

        float4 w20 = *(const float4*)(Wh2 + k0);
        float4 w21 = *(const float4*)(Wh2 + k0 + 4);

        float e0 = edge_p(wh10, w20.x, aj0a.x), e1 = edge_p(wh10, w20.y, aj0a.y);
        float e2 = edge_p(wh10, w20.z, aj0a.z), e3 = edge_p(wh10, w20.w, aj0a.w);
        float e4 = edge_p(wh10, w21.x, aj0b.x), e5 = edge_p(wh10, w21.y, aj0b.y);
        float e6 = edge_p(wh10, w21.z, aj0b.z), e7 = edge_p(wh10, w21.w, aj0b.w);
        ps0 += ((e0 + e1) + (e2 + e3)) + ((e4 + e5) + (e6 + e7));
        u32x4 uv0;
        uv0.x = packbf2(e0, e1); uv0.y = packbf2(e2, e3);
        uv0.z = packbf2(e4, e5); uv0.w = packbf2(e6, e7);

        float f0 = edge_p(wh11, w20.x, aj1a.x), f1 = edge_p(wh11, w20.y, aj1a.y);
        float f2 = edge_p(wh11, w20.z, aj1a.z), f3 = edge_p(wh11, w20.w, aj1a.w);
        float f4 = edge_p(wh11, w21.x, aj1b.x), f5 = edge_p(wh11, w21.y, aj1b.y);
        float f6 = edge_p(wh11, w21.z, aj1b.z), f7 = edge_p(wh11, w21.w, aj1b.w);
        ps1 += ((f0 + f1) + (f2 + f3)) + ((f4 + f5) + (f6 + f7));
        u32x4 uv1;
        uv1.x = packbf2(f0, f1); uv1.y = packbf2(f2, f3);
        uv1.z = packbf2(f4, f5); uv1.w = packbf2(f6, f7);

        s16x8 af0 = __builtin_bit_cast(s16x8, uv0);
        s16x8 af1 = __builtin_bit_cast(s16x8, uv1);

        #pragma unroll
        for (int nt = 0; nt < 8; nt++) {
            s16x8 b = Hf[(kt * 8 + nt) * 64 + lane];
            acc0[nt] = __builtin_amdgcn_mfma_f32_16x16x32_bf16(af0, b, acc0[nt], 0, 0, 0);
            acc1[nt] = __builtin_amdgcn_mfma_f32_16x16x32_bf16(af1, b, acc1[nt], 0, 0, 0);
        }
    }

    ps0 += __shfl_xor(ps0, 16, 64); ps0 += __shfl_xor(ps0, 32, 64);
    ps1 += __shfl_xor(ps1, 16, 64); ps1 += __shfl_xor(ps1, 32, 64);
    if (quad == 0) {
        sum_part[(size_t)kh * N_NODES + r0] = ps0;
        sum_part[(size_t)kh * N_NODES + r1] = ps1;
    }

    #pragma unroll
    for (int nt = 0; nt < 8; nt++) {
        #pragma unroll
        for (int reg = 0; reg < 4; reg++) {
            int row0 = rbase + quad * 4 + reg;
            int col = nt * 16 + lid;
            out_part[((size_t)kh * N_NODES + row0) * OUT_F + col] = acc0[nt][reg];
            out_part[((size_t)kh * N_NODES + row0 + 16) * OUT_F + col] = acc1[nt][reg];
        }
    }
}

// ---- K3: out = (sum_k part_k) / (sum_k rowsum_k)
__global__ void finalize(const float* __restrict__ out_part,
                         const float* __restrict__ sum_part,
                         float* __restrict__ out) {
    int gid = blockIdx.x * 256 + threadIdx.x;
    int i = gid >> 7;
    float s = 0.f, v = 0.f;
    for (int kh = 0; kh < KP; kh++) {
        s += sum_part[(size_t)kh * N_NODES + i];
        v += out_part[(size_t)kh * N_NODES * OUT_F + gid];
    }
    out[gid] = v / s;
}

extern "C" void kernel_launch(void* const* d_in, const int* in_sizes, int n_in,
                              void* d_out, int out_size, void* d_ws, size_t ws_size,
                              hipStream_t stream) {
    const float* X   = (const float*)d_in[0];
    const int*   adj = (const int*)d_in[1];
    const float* W   = (const float*)d_in[2];
    const float* a1  = (const float*)d_in[3];
    const float* a2  = (const float*)d_in[4];

    const size_t BASE = (size_t)4 << 20;   // fixed region: Wh/Wa/W_frag/h_frag
    char* ws = (char*)d_ws;
    float* Wh1 = (float*)(ws);                         // 32 KB
    float* Wh2 = (float*)(ws + (32 << 10));            // 32 KB
    float* Wa1 = (float*)(ws + (64 << 10));            // 2 KB
    float* Wa2 = (float*)(ws + (66 << 10));            // 2 KB
    u16* W_frag = (u16*)(ws + (128 << 10));            // 128 KB
    u16* h_frag = (u16*)(ws + (256 << 10));            // 2 MB (ends at 2.25 MB < 4 MB)
    float* out_part = (float*)(ws + BASE);             // KP * 4 MB = 64 MB
    float* sum_part = (float*)(ws + BASE + ((size_t)KP << 22));  // KP * 32 KB
    float* out = (float*)d_out;

    hipLaunchKernelGGL(repack_W, dim3(256), dim3(256), 0, stream, W, W_frag);
    hipLaunchKernelGGL(compute_Wa, dim3(2), dim3(256), 0, stream, W, a1, a2, Wa1, Wa2);
    hipLaunchKernelGGL(gemm_h, dim3(512), dim3(256), 0, stream,
                       X, W_frag, Wa1, Wa2, Wh1, Wh2, h_frag);
    hipLaunchKernelGGL(attn_kernel, dim3(64 * KP), dim3(256), 0, stream,
                       adj, Wh1, Wh2, h_frag, out_part, sum_part);
    hipLaunchKernelGGL(finalize, dim3((N_NODES * OUT_F) / 256), dim3(256), 0, stream,
                       out_part, sum_part, out);
}